// Round 1
// baseline (393.814 us; speedup 1.0000x reference)
//
#include <hip/hip_runtime.h>
#include <hip/hip_bf16.h>
#include <stdint.h>

// Qwen3 MLP with QDQ fake-quant, MI355X gfx950.
// M=8192 (B*S), H=1024, I=3072.
// R5: kgemm1 fused dual-B single-pass: stage A(xq) once per K-step with BOTH
// B tiles (up, gate), BK=64 -> 64 MFMA per barrier-pair (was 16), barrier
// count per block 136 -> 40, A staged once (was twice). hbuf deleted: g and
// u coexist in registers, so h/o amaxes come straight from the accumulators.
// BK=64 XOR swizzle: phys_chunk = chunk ^ (row&7) (2-way = free).
// kgemm2 moved to the same BK=64 core.

#define M_ROWS 8192
#define H_DIM 1024
#define I_DIM 3072

typedef unsigned short u16;
typedef unsigned int u32;
typedef __attribute__((ext_vector_type(8))) short bf16x8;
typedef __attribute__((ext_vector_type(4))) float f32x4;

__device__ __forceinline__ float bf2f(u16 v) { return __uint_as_float(((u32)v) << 16); }
__device__ __forceinline__ u16 f2bf(float f) {
  u32 u = __float_as_uint(f);
  u32 r = (u + 0x7fffu + ((u >> 16) & 1u)) >> 16;
  return (u16)r;
}
__device__ __forceinline__ float qdq16i(float x, float inv, float s) {
  float q = rintf(x * inv);
  q = fminf(fmaxf(q, -32768.f), 32767.f);
  return q * s;
}
// fixed u16 sigmoid grid
__device__ __forceinline__ float sigq(float g) {
  float sig = __builtin_amdgcn_rcpf(1.f + __expf(-g));
  return fminf(fmaxf(rintf(sig * 65536.f), 0.f), 65535.f) * (1.f / 65536.f);
}

// scal: u32[16][16]; sub-slot j of slot s at scal[j*16+s] (16 distinct 64B lines)
// slots: 0=x 1=up 2=gate 3=h 4=o
__device__ __forceinline__ float scale_read(const u32* __restrict__ scal, int s) {
  u32 m = 0;
#pragma unroll
  for (int j = 0; j < 16; ++j) m = max(m, scal[j * 16 + s]);
  return fmaxf(__uint_as_float(m) / 32767.f, 1e-12f);
}

__device__ __forceinline__ void load_lds16(const u16* g, u16* lds) {
  __builtin_amdgcn_global_load_lds(
      (const __attribute__((address_space(1))) u32*)g,
      (__attribute__((address_space(3))) u32*)lds, 16, 0, 0);
}

__device__ __forceinline__ void block_amax_atomic(float mx, u32* scal, int s) {
#pragma unroll
  for (int off = 32; off; off >>= 1) mx = fmaxf(mx, __shfl_xor(mx, off));
  __shared__ float red[4];
  const int lane = threadIdx.x & 63, wave = threadIdx.x >> 6;
  if (lane == 0) red[wave] = mx;
  __syncthreads();
  if (threadIdx.x == 0) {
    float m = fmaxf(fmaxf(red[0], red[1]), fmaxf(red[2], red[3]));
    atomicMax(scal + (blockIdx.x & 15) * 16 + s, __float_as_uint(m));
  }
}

// four amaxes, one barrier; slots 1=up 2=gate 3=h 4=o
__device__ __forceinline__ void block_amax4(float a, float b, float c, float d,
                                            u32* __restrict__ scal) {
#pragma unroll
  for (int off = 32; off; off >>= 1) {
    a = fmaxf(a, __shfl_xor(a, off));
    b = fmaxf(b, __shfl_xor(b, off));
    c = fmaxf(c, __shfl_xor(c, off));
    d = fmaxf(d, __shfl_xor(d, off));
  }
  __shared__ float red4[4][4];
  const int lane = threadIdx.x & 63, wave = threadIdx.x >> 6;
  if (lane == 0) {
    red4[0][wave] = a;
    red4[1][wave] = b;
    red4[2][wave] = c;
    red4[3][wave] = d;
  }
  __syncthreads();
  if (threadIdx.x == 0) {
    u32* base = scal + (blockIdx.x & 15) * 16;
#pragma unroll
    for (int s = 0; s < 4; ++s) {
      float m = fmaxf(fmaxf(red4[s][0], red4[s][1]), fmaxf(red4[s][2], red4[s][3]));
      atomicMax(base + 1 + s, __float_as_uint(m));
    }
  }
}

// ---------------- GEMM core, BK=64 (single B) ----------------
// C[m,n] = sum_k A[m,k]*B[n,k]; row-major, row stride K (bf16 elems).
// 128x128 tile, BK=64, 4 waves each 64x64 via 4x4 MFMA 16x16x32.
// LDS tile 128x64 u16; chunk q (8 u16) of row r stored at phys chunk
// q^(r&7): rows sharing a phys chunk are 8 apart = 1024B = same-bank 2-way
// (free, m136). global_load_lds dest linear; source pre-swizzled.
template <int K>
__device__ __forceinline__ void gemm_core64(const u16* __restrict__ Ablk,
                                            const u16* __restrict__ Bblk,
                                            f32x4 acc[4][4], u16* smem) {
  u16* As = smem;          // 128*64
  u16* Bs = smem + 8192;   // 128*64
  const int tid = threadIdx.x;
  const int lane = tid & 63, wave = tid >> 6;
  const int wm = wave >> 1, wn = wave & 1;
  const int quad = lane >> 4, mrow = lane & 15;

  int goff[4], loff[4];
#pragma unroll
  for (int t = 0; t < 4; ++t) {
    const int c = tid + 256 * t;
    const int r = c >> 3, q = c & 7;
    goff[t] = r * K + ((q ^ (r & 7)) << 3);
    loff[t] = c << 3;
  }
  // fragment row&7 == mrow&7 (rows step by 16)
  const int pc0 = (quad ^ (mrow & 7)) << 3;
  const int pc1 = ((quad + 4) ^ (mrow & 7)) << 3;
  int arow[4], brow[4];
#pragma unroll
  for (int i = 0; i < 4; ++i) {
    arow[i] = (wm * 64 + i * 16 + mrow) << 6;
    brow[i] = (wn * 64 + i * 16 + mrow) << 6;
  }

  for (int k0 = 0; k0 < K; k0 += 64) {
    __syncthreads();
#pragma unroll
    for (int t = 0; t < 4; ++t) {
      load_lds16(Ablk + k0 + goff[t], As + loff[t]);
      load_lds16(Bblk + k0 + goff[t], Bs + loff[t]);
    }
    __syncthreads();
#pragma unroll
    for (int kk = 0; kk < 2; ++kk) {
      const int pc = kk ? pc1 : pc0;
      bf16x8 af[4], bfr[4];
#pragma unroll
      for (int t = 0; t < 4; ++t) {
        af[t] = *(const bf16x8*)&As[arow[t] + pc];
        bfr[t] = *(const bf16x8*)&Bs[brow[t] + pc];
      }
#pragma unroll
      for (int i = 0; i < 4; ++i)
#pragma unroll
        for (int j = 0; j < 4; ++j)
          acc[i][j] = __builtin_amdgcn_mfma_f32_16x16x32_bf16(af[i], bfr[j], acc[i][j], 0, 0, 0);
    }
  }
}

// GEMM1 fused: one K-loop computes gate AND up for the same (m,n) tile.
// Epilogue: g,u in registers -> amax(up)=1, amax(gate)=2, amax(h)=3,
// amax(o)=4 (h,o approximate: qdq-snap skipped, scale rel-err ~0.4% ->
// <1e-3 final absmax impact, same approximation family as R4).
__global__ void __launch_bounds__(256) kgemm1(const u16* __restrict__ xq,
                                              const u16* __restrict__ wcat,
                                              u16* __restrict__ up, u16* __restrict__ gh,
                                              u32* __restrict__ scal) {
  __shared__ __align__(16) u16 smem[24576];  // As | Bus | Bgs = 48 KiB
  u16* As = smem;
  u16* Bus = smem + 8192;
  u16* Bgs = smem + 16384;
  const int tileN = blockIdx.x * 128;
  const int tileM = blockIdx.y * 128;
  const int tid = threadIdx.x;
  const int lane = tid & 63, wave = tid >> 6;
  const int wm = wave >> 1, wn = wave & 1;
  const int quad = lane >> 4, mrow = lane & 15;

  const u16* Ablk = xq + (size_t)tileM * H_DIM;
  const u16* Bublk = wcat + (size_t)tileN * H_DIM;
  const u16* Bgblk = wcat + (size_t)(I_DIM + tileN) * H_DIM;

  int goff[4], loff[4];
#pragma unroll
  for (int t = 0; t < 4; ++t) {
    const int c = tid + 256 * t;
    const int r = c >> 3, q = c & 7;
    goff[t] = r * H_DIM + ((q ^ (r & 7)) << 3);
    loff[t] = c << 3;
  }
  const int pc0 = (quad ^ (mrow & 7)) << 3;
  const int pc1 = ((quad + 4) ^ (mrow & 7)) << 3;
  int arow[4], brow[4];
#pragma unroll
  for (int i = 0; i < 4; ++i) {
    arow[i] = (wm * 64 + i * 16 + mrow) << 6;
    brow[i] = (wn * 64 + i * 16 + mrow) << 6;
  }

  f32x4 accg[4][4], accu[4][4];
#pragma unroll
  for (int i = 0; i < 4; ++i)
#pragma unroll
    for (int j = 0; j < 4; ++j) {
      accg[i][j] = (f32x4){0.f, 0.f, 0.f, 0.f};
      accu[i][j] = (f32x4){0.f, 0.f, 0.f, 0.f};
    }

  for (int k0 = 0; k0 < H_DIM; k0 += 64) {
    __syncthreads();
#pragma unroll
    for (int t = 0; t < 4; ++t) {
      load_lds16(Ablk + k0 + goff[t], As + loff[t]);
      load_lds16(Bublk + k0 + goff[t], Bus + loff[t]);
      load_lds16(Bgblk + k0 + goff[t], Bgs + loff[t]);
    }
    __syncthreads();
#pragma unroll
    for (int kk = 0; kk < 2; ++kk) {
      const int pc = kk ? pc1 : pc0;
      bf16x8 af[4], bfu[4], bfg[4];
#pragma unroll
      for (int t = 0; t < 4; ++t) {
        af[t] = *(const bf16x8*)&As[arow[t] + pc];
        bfu[t] = *(const bf16x8*)&Bus[brow[t] + pc];
      }
#pragma unroll
      for (int i = 0; i < 4; ++i)
#pragma unroll
        for (int j = 0; j < 4; ++j)
          accu[i][j] = __builtin_amdgcn_mfma_f32_16x16x32_bf16(af[i], bfu[j], accu[i][j], 0, 0, 0);
#pragma unroll
      for (int t = 0; t < 4; ++t) bfg[t] = *(const bf16x8*)&Bgs[brow[t] + pc];
#pragma unroll
      for (int i = 0; i < 4; ++i)
#pragma unroll
        for (int j = 0; j < 4; ++j)
          accg[i][j] = __builtin_amdgcn_mfma_f32_16x16x32_bf16(af[i], bfg[j], accg[i][j], 0, 0, 0);
    }
  }

  // ---------------- epilogue: both tiles + 4 amaxes ----------------
  const int rb = (lane >> 4) * 4, cb = lane & 15;  // C/D: row=(l>>4)*4+reg, col=l&15
  const int erow = lane >> 2, echk = lane & 3;
  u16* gstage = smem + wave * 1152;          // 16 rows * 72 per wave (in As area)
  u16* ustage = smem + 8192 + wave * 1152;   // in Bus area
  const u16* grb = gstage + erow * 72;
  const u16* urb = ustage + erow * 72;
  float mxg = 0.f, mxu = 0.f, mxh = 0.f, mxo = 0.f;
#pragma unroll
  for (int i = 0; i < 4; ++i) {
    __syncthreads();
#pragma unroll
    for (int j = 0; j < 4; ++j)
#pragma unroll
      for (int r = 0; r < 4; ++r) {
        float g = accg[i][j][r];
        float u = accu[i][j][r];
        mxg = fmaxf(mxg, fabsf(g));
        mxu = fmaxf(mxu, fabsf(u));
        float ha = g * sigq(g);
        mxh = fmaxf(mxh, fabsf(ha));
        mxo = fmaxf(mxo, fabsf(ha * u));
        gstage[(rb + r) * 72 + j * 16 + cb] = f2bf(g);
        ustage[(rb + r) * 72 + j * 16 + cb] = f2bf(u);
      }
    __syncthreads();
    uint4 g0 = *(const uint4*)(grb + echk * 8);
    uint4 g1 = *(const uint4*)(grb + (echk + 4) * 8);
    uint4 u0 = *(const uint4*)(urb + echk * 8);
    uint4 u1 = *(const uint4*)(urb + (echk + 4) * 8);
    size_t grow = (size_t)(tileM + wm * 64 + i * 16 + erow) * I_DIM + (tileN + wn * 64);
    *(uint4*)(gh + grow + echk * 8) = g0;
    *(uint4*)(gh + grow + (echk + 4) * 8) = g1;
    *(uint4*)(up + grow + echk * 8) = u0;
    *(uint4*)(up + grow + (echk + 4) * 8) = u1;
  }
  block_amax4(mxu, mxg, mxh, mxo, scal);
}

// GEMM2: oq[8192,3072] x wdq[1024,3072]^T -> out fp32 [8192,1024]
__global__ void __launch_bounds__(256) kgemm2(const u16* __restrict__ oq,
                                              const u16* __restrict__ wdq,
                                              float* __restrict__ out) {
  __shared__ __align__(16) u16 smem[16384];  // 32 KiB
  const int tileN = blockIdx.x * 128;
  const int tileM = blockIdx.y * 128;
  f32x4 acc[4][4];
#pragma unroll
  for (int i = 0; i < 4; ++i)
#pragma unroll
    for (int j = 0; j < 4; ++j) acc[i][j] = (f32x4){0.f, 0.f, 0.f, 0.f};
  gemm_core64<I_DIM>(oq + (size_t)tileM * I_DIM, wdq + (size_t)tileN * I_DIM, acc, smem);

  const int lane = threadIdx.x & 63, wave = threadIdx.x >> 6;
  const int wm = wave >> 1, wn = wave & 1;
  const int rb = (lane >> 4) * 4, cb = lane & 15;
#pragma unroll
  for (int i = 0; i < 4; ++i) {
#pragma unroll
    for (int j = 0; j < 4; ++j) {
      size_t base = (size_t)(tileM + wm * 64 + i * 16 + rb) * H_DIM +
                    (size_t)(tileN + wn * 64 + j * 16 + cb);
#pragma unroll
      for (int r = 0; r < 4; ++r) out[base + (size_t)r * H_DIM] = acc[i][j][r];
    }
  }
}

// ---------------- prep: absmax(x) (blocks 0..1023) + LPBQ dequant (rest) ----
__global__ void __launch_bounds__(256) kprep(const float* __restrict__ x,
                                             const float* __restrict__ wu,
                                             const float* __restrict__ wg,
                                             const float* __restrict__ wdn,
                                             u16* __restrict__ wcat, u16* __restrict__ wdq,
                                             u32* __restrict__ scal) {
  if (blockIdx.x < 1024) {
    const float4* x4 = (const float4*)x;
    const int n4 = (M_ROWS * H_DIM) / 4;
    float mx = 0.f;
    for (int i = blockIdx.x * 256 + threadIdx.x; i < n4; i += 1024 * 256) {
      float4 v = x4[i];
      mx = fmaxf(fmaxf(fabsf(v.x), fabsf(v.y)), fmaxf(fmaxf(fabsf(v.z), fabsf(v.w)), mx));
    }
    block_amax_atomic(mx, scal, 0);
    return;
  }
  const int gid = (blockIdx.x - 1024) * 256 + threadIdx.x;
  const int unit = gid >> 3, l8 = gid & 7;
  const float* src;
  u16* dst;
  int u;
  if (unit < 98304)       { src = wu;  dst = wcat;            u = unit; }
  else if (unit < 196608) { src = wg;  dst = wcat + 3145728;  u = unit - 98304; }
  else                    { src = wdn; dst = wdq;             u = unit - 196608; }
  const size_t off = (size_t)u * 32 + (size_t)l8 * 4;
  float4 v = *(const float4*)(src + off);
  float m = fmaxf(fmaxf(fabsf(v.x), fabsf(v.y)), fmaxf(fabsf(v.z), fabsf(v.w)));
  m = fmaxf(m, __shfl_xor(m, 1));
  m = fmaxf(m, __shfl_xor(m, 2));
  m = fmaxf(m, __shfl_xor(m, 4));
  const float s = fmaxf(m / 7.0f, 1e-12f);
  const float inv = 1.0f / s;
  float vv[4] = {v.x, v.y, v.z, v.w};
  u16 o[4];
#pragma unroll
  for (int e = 0; e < 4; ++e) {
    float q = rintf(vv[e] * inv);
    q = fminf(fmaxf(q, -8.f), 7.f);
    o[e] = f2bf(q * s);
  }
  *(ushort4*)(dst + off) = make_ushort4(o[0], o[1], o[2], o[3]);
}

__global__ void __launch_bounds__(256) kqdqx(const float4* __restrict__ x,
                                             ushort4* __restrict__ xq,
                                             const u32* __restrict__ scal) {
  const float s = scale_read(scal, 0);
  const float inv = 1.0f / s;
  const int i = blockIdx.x * 256 + threadIdx.x;
  float4 v = x[i];
  ushort4 o;
  o.x = f2bf(qdq16i(v.x, inv, s));
  o.y = f2bf(qdq16i(v.y, inv, s));
  o.z = f2bf(qdq16i(v.z, inv, s));
  o.w = f2bf(qdq16i(v.w, inv, s));
  xq[i] = o;
}

#define GH4 ((M_ROWS * I_DIM) / 8)
#define EW_BLOCKS 2048

// exact chain: g_q=qdq(g,sg); h=g_q*sigq(g_q); h_q=qdq(h,sh);
// o=h_q*qdq(u,su); oq=bf16(qdq(o,so)) -> gh (in place)
__global__ void __launch_bounds__(256) kmulo(uint4* __restrict__ gh, const uint4* __restrict__ up,
                                             u32* __restrict__ scal) {
  const float sg = scale_read(scal, 2), ig = 1.0f / sg;
  const float sh = scale_read(scal, 3), ih = 1.0f / sh;
  const float su = scale_read(scal, 1), iu = 1.0f / su;
  const float so = scale_read(scal, 4), io = 1.0f / so;
  for (int i = blockIdx.x * 256 + threadIdx.x; i < GH4; i += EW_BLOCKS * 256) {
    union { uint4 v; u16 us[8]; } a, b;
    a.v = gh[i];
    b.v = up[i];
#pragma unroll
    for (int e = 0; e < 8; ++e) {
      float g = qdq16i(bf2f(a.us[e]), ig, sg);
      float h = g * sigq(g);
      float o = qdq16i(h, ih, sh) * qdq16i(bf2f(b.us[e]), iu, su);
      a.us[e] = f2bf(qdq16i(o, io, so));
    }
    gh[i] = a.v;
  }
}

extern "C" void kernel_launch(void* const* d_in, const int* in_sizes, int n_in,
                              void* d_out, int out_size, void* d_ws, size_t ws_size,
                              hipStream_t stream) {
  (void)in_sizes; (void)n_in; (void)out_size; (void)ws_size;
  const float* x   = (const float*)d_in[0];
  const float* wg  = (const float*)d_in[1];
  const float* wu  = (const float*)d_in[2];
  const float* wdn = (const float*)d_in[3];
  float* out = (float*)d_out;
  char* ws = (char*)d_ws;

  u32* scal = (u32*)ws;
  u16* xq   = (u16*)(ws + 1024);                    // 8192*1024
  u16* wcat = xq + (size_t)M_ROWS * H_DIM;          // 6144*1024 (up rows, then gate rows)
  u16* wdq  = wcat + (size_t)2 * I_DIM * H_DIM;     // 1024*3072
  u16* up   = wdq + (size_t)H_DIM * I_DIM;          // 8192*3072
  u16* gh   = up + (size_t)M_ROWS * I_DIM;          // 8192*3072 (gate -> oq)

  hipMemsetAsync(scal, 0, 1024, stream);
  kprep<<<1024 + 9216, 256, 0, stream>>>(x, wu, wg, wdn, wcat, wdq, scal);
  kqdqx<<<(M_ROWS * H_DIM) / 4 / 256, 256, 0, stream>>>((const float4*)x, (ushort4*)xq, scal);
  kgemm1<<<dim3(24, 64), 256, 0, stream>>>(xq, wcat, up, gh, scal);
  kmulo<<<EW_BLOCKS, 256, 0, stream>>>((uint4*)gh, (const uint4*)up, scal);
  kgemm2<<<dim3(8, 64), 256, 0, stream>>>(gh, wdq, out);
}

// Round 2
// 323.257 us; speedup vs baseline: 1.2183x; 1.2183x over previous
//
#include <hip/hip_runtime.h>
#include <hip/hip_bf16.h>
#include <stdint.h>

// Qwen3 MLP with QDQ fake-quant, MI355X gfx950.
// M=8192 (B*S), H=1024, I=3072.
// R6: R5's fused dual-B kgemm1 had combined regs 164 VGPR + 128 AGPR = 292
// -> 1 wave/SIMD -> 1 block/CU (Occupancy 11.2%) -> barrier drains exposed.
// Fix: __launch_bounds__(256,2) caps combined at 256 (2 blocks/CU), and the
// inner MFMA loops load ONE B fragment at a time (max live frags 16+8 not 48)
// so the cap doesn't force K-loop spills.

#define M_ROWS 8192
#define H_DIM 1024
#define I_DIM 3072

typedef unsigned short u16;
typedef unsigned int u32;
typedef __attribute__((ext_vector_type(8))) short bf16x8;
typedef __attribute__((ext_vector_type(4))) float f32x4;

__device__ __forceinline__ float bf2f(u16 v) { return __uint_as_float(((u32)v) << 16); }
__device__ __forceinline__ u16 f2bf(float f) {
  u32 u = __float_as_uint(f);
  u32 r = (u + 0x7fffu + ((u >> 16) & 1u)) >> 16;
  return (u16)r;
}
__device__ __forceinline__ float qdq16i(float x, float inv, float s) {
  float q = rintf(x * inv);
  q = fminf(fmaxf(q, -32768.f), 32767.f);
  return q * s;
}
// fixed u16 sigmoid grid
__device__ __forceinline__ float sigq(float g) {
  float sig = __builtin_amdgcn_rcpf(1.f + __expf(-g));
  return fminf(fmaxf(rintf(sig * 65536.f), 0.f), 65535.f) * (1.f / 65536.f);
}

// scal: u32[16][16]; sub-slot j of slot s at scal[j*16+s] (16 distinct 64B lines)
// slots: 0=x 1=up 2=gate 3=h 4=o
__device__ __forceinline__ float scale_read(const u32* __restrict__ scal, int s) {
  u32 m = 0;
#pragma unroll
  for (int j = 0; j < 16; ++j) m = max(m, scal[j * 16 + s]);
  return fmaxf(__uint_as_float(m) / 32767.f, 1e-12f);
}

__device__ __forceinline__ void load_lds16(const u16* g, u16* lds) {
  __builtin_amdgcn_global_load_lds(
      (const __attribute__((address_space(1))) u32*)g,
      (__attribute__((address_space(3))) u32*)lds, 16, 0, 0);
}

__device__ __forceinline__ void block_amax_atomic(float mx, u32* scal, int s) {
#pragma unroll
  for (int off = 32; off; off >>= 1) mx = fmaxf(mx, __shfl_xor(mx, off));
  __shared__ float red[4];
  const int lane = threadIdx.x & 63, wave = threadIdx.x >> 6;
  if (lane == 0) red[wave] = mx;
  __syncthreads();
  if (threadIdx.x == 0) {
    float m = fmaxf(fmaxf(red[0], red[1]), fmaxf(red[2], red[3]));
    atomicMax(scal + (blockIdx.x & 15) * 16 + s, __float_as_uint(m));
  }
}

// four amaxes, one barrier; slots 1=up 2=gate 3=h 4=o
__device__ __forceinline__ void block_amax4(float a, float b, float c, float d,
                                            u32* __restrict__ scal) {
#pragma unroll
  for (int off = 32; off; off >>= 1) {
    a = fmaxf(a, __shfl_xor(a, off));
    b = fmaxf(b, __shfl_xor(b, off));
    c = fmaxf(c, __shfl_xor(c, off));
    d = fmaxf(d, __shfl_xor(d, off));
  }
  __shared__ float red4[4][4];
  const int lane = threadIdx.x & 63, wave = threadIdx.x >> 6;
  if (lane == 0) {
    red4[0][wave] = a;
    red4[1][wave] = b;
    red4[2][wave] = c;
    red4[3][wave] = d;
  }
  __syncthreads();
  if (threadIdx.x == 0) {
    u32* base = scal + (blockIdx.x & 15) * 16;
#pragma unroll
    for (int s = 0; s < 4; ++s) {
      float m = fmaxf(fmaxf(red4[s][0], red4[s][1]), fmaxf(red4[s][2], red4[s][3]));
      atomicMax(base + 1 + s, __float_as_uint(m));
    }
  }
}

// ---------------- GEMM core, BK=64 (single B) ----------------
// C[m,n] = sum_k A[m,k]*B[n,k]; row-major, row stride K (bf16 elems).
// 128x128 tile, BK=64, 4 waves each 64x64 via 4x4 MFMA 16x16x32.
// LDS tile 128x64 u16; chunk q (8 u16) of row r stored at phys chunk
// q^(r&7): rows sharing a phys chunk are 8 apart = 1024B = same-bank 2-way
// (free, m136). global_load_lds dest linear; source pre-swizzled.
template <int K>
__device__ __forceinline__ void gemm_core64(const u16* __restrict__ Ablk,
                                            const u16* __restrict__ Bblk,
                                            f32x4 acc[4][4], u16* smem) {
  u16* As = smem;          // 128*64
  u16* Bs = smem + 8192;   // 128*64
  const int tid = threadIdx.x;
  const int lane = tid & 63, wave = tid >> 6;
  const int wm = wave >> 1, wn = wave & 1;
  const int quad = lane >> 4, mrow = lane & 15;

  int goff[4], loff[4];
#pragma unroll
  for (int t = 0; t < 4; ++t) {
    const int c = tid + 256 * t;
    const int r = c >> 3, q = c & 7;
    goff[t] = r * K + ((q ^ (r & 7)) << 3);
    loff[t] = c << 3;
  }
  // fragment row&7 == mrow&7 (rows step by 16)
  const int pc0 = (quad ^ (mrow & 7)) << 3;
  const int pc1 = ((quad + 4) ^ (mrow & 7)) << 3;
  int arow[4], brow[4];
#pragma unroll
  for (int i = 0; i < 4; ++i) {
    arow[i] = (wm * 64 + i * 16 + mrow) << 6;
    brow[i] = (wn * 64 + i * 16 + mrow) << 6;
  }

  for (int k0 = 0; k0 < K; k0 += 64) {
    __syncthreads();
#pragma unroll
    for (int t = 0; t < 4; ++t) {
      load_lds16(Ablk + k0 + goff[t], As + loff[t]);
      load_lds16(Bblk + k0 + goff[t], Bs + loff[t]);
    }
    __syncthreads();
#pragma unroll
    for (int kk = 0; kk < 2; ++kk) {
      const int pc = kk ? pc1 : pc0;
      bf16x8 af[4];
#pragma unroll
      for (int t = 0; t < 4; ++t) af[t] = *(const bf16x8*)&As[arow[t] + pc];
#pragma unroll
      for (int j = 0; j < 4; ++j) {
        bf16x8 b = *(const bf16x8*)&Bs[brow[j] + pc];
#pragma unroll
        for (int i = 0; i < 4; ++i)
          acc[i][j] = __builtin_amdgcn_mfma_f32_16x16x32_bf16(af[i], b, acc[i][j], 0, 0, 0);
      }
    }
  }
}

// GEMM1 fused: one K-loop computes gate AND up for the same (m,n) tile.
// Epilogue: g,u in registers -> amax(up)=1, amax(gate)=2, amax(h)=3,
// amax(o)=4 (h,o approximate: qdq-snap skipped, scale rel-err ~0.4% ->
// <1e-3 final absmax impact, same approximation family as R4).
// launch_bounds(256,2): cap combined VGPR+AGPR at 256 -> 2 blocks/CU.
__global__ void __launch_bounds__(256, 2) kgemm1(const u16* __restrict__ xq,
                                                 const u16* __restrict__ wcat,
                                                 u16* __restrict__ up, u16* __restrict__ gh,
                                                 u32* __restrict__ scal) {
  __shared__ __align__(16) u16 smem[24576];  // As | Bus | Bgs = 48 KiB
  u16* As = smem;
  u16* Bus = smem + 8192;
  u16* Bgs = smem + 16384;
  const int tileN = blockIdx.x * 128;
  const int tileM = blockIdx.y * 128;
  const int tid = threadIdx.x;
  const int lane = tid & 63, wave = tid >> 6;
  const int wm = wave >> 1, wn = wave & 1;
  const int quad = lane >> 4, mrow = lane & 15;

  const u16* Ablk = xq + (size_t)tileM * H_DIM;
  const u16* Bublk = wcat + (size_t)tileN * H_DIM;
  const u16* Bgblk = wcat + (size_t)(I_DIM + tileN) * H_DIM;

  int goff[4], loff[4];
#pragma unroll
  for (int t = 0; t < 4; ++t) {
    const int c = tid + 256 * t;
    const int r = c >> 3, q = c & 7;
    goff[t] = r * H_DIM + ((q ^ (r & 7)) << 3);
    loff[t] = c << 3;
  }
  const int pc0 = (quad ^ (mrow & 7)) << 3;
  const int pc1 = ((quad + 4) ^ (mrow & 7)) << 3;
  int arow[4], brow[4];
#pragma unroll
  for (int i = 0; i < 4; ++i) {
    arow[i] = (wm * 64 + i * 16 + mrow) << 6;
    brow[i] = (wn * 64 + i * 16 + mrow) << 6;
  }

  f32x4 accg[4][4], accu[4][4];
#pragma unroll
  for (int i = 0; i < 4; ++i)
#pragma unroll
    for (int j = 0; j < 4; ++j) {
      accg[i][j] = (f32x4){0.f, 0.f, 0.f, 0.f};
      accu[i][j] = (f32x4){0.f, 0.f, 0.f, 0.f};
    }

  for (int k0 = 0; k0 < H_DIM; k0 += 64) {
    __syncthreads();
#pragma unroll
    for (int t = 0; t < 4; ++t) {
      load_lds16(Ablk + k0 + goff[t], As + loff[t]);
      load_lds16(Bublk + k0 + goff[t], Bus + loff[t]);
      load_lds16(Bgblk + k0 + goff[t], Bgs + loff[t]);
    }
    __syncthreads();
#pragma unroll
    for (int kk = 0; kk < 2; ++kk) {
      const int pc = kk ? pc1 : pc0;
      bf16x8 af[4];
#pragma unroll
      for (int t = 0; t < 4; ++t) af[t] = *(const bf16x8*)&As[arow[t] + pc];
      // one B fragment live at a time: keeps peak regs under the 256 cap
#pragma unroll
      for (int j = 0; j < 4; ++j) {
        bf16x8 b = *(const bf16x8*)&Bus[brow[j] + pc];
#pragma unroll
        for (int i = 0; i < 4; ++i)
          accu[i][j] = __builtin_amdgcn_mfma_f32_16x16x32_bf16(af[i], b, accu[i][j], 0, 0, 0);
      }
#pragma unroll
      for (int j = 0; j < 4; ++j) {
        bf16x8 b = *(const bf16x8*)&Bgs[brow[j] + pc];
#pragma unroll
        for (int i = 0; i < 4; ++i)
          accg[i][j] = __builtin_amdgcn_mfma_f32_16x16x32_bf16(af[i], b, accg[i][j], 0, 0, 0);
      }
    }
  }

  // ---------------- epilogue: both tiles + 4 amaxes ----------------
  const int rb = (lane >> 4) * 4, cb = lane & 15;  // C/D: row=(l>>4)*4+reg, col=l&15
  const int erow = lane >> 2, echk = lane & 3;
  u16* gstage = smem + wave * 1152;          // 16 rows * 72 per wave (in As area)
  u16* ustage = smem + 8192 + wave * 1152;   // in Bus area
  const u16* grb = gstage + erow * 72;
  const u16* urb = ustage + erow * 72;
  float mxg = 0.f, mxu = 0.f, mxh = 0.f, mxo = 0.f;
#pragma unroll
  for (int i = 0; i < 4; ++i) {
    __syncthreads();
#pragma unroll
    for (int j = 0; j < 4; ++j)
#pragma unroll
      for (int r = 0; r < 4; ++r) {
        float g = accg[i][j][r];
        float u = accu[i][j][r];
        mxg = fmaxf(mxg, fabsf(g));
        mxu = fmaxf(mxu, fabsf(u));
        float ha = g * sigq(g);
        mxh = fmaxf(mxh, fabsf(ha));
        mxo = fmaxf(mxo, fabsf(ha * u));
        gstage[(rb + r) * 72 + j * 16 + cb] = f2bf(g);
        ustage[(rb + r) * 72 + j * 16 + cb] = f2bf(u);
      }
    __syncthreads();
    uint4 g0 = *(const uint4*)(grb + echk * 8);
    uint4 g1 = *(const uint4*)(grb + (echk + 4) * 8);
    uint4 u0 = *(const uint4*)(urb + echk * 8);
    uint4 u1 = *(const uint4*)(urb + (echk + 4) * 8);
    size_t grow = (size_t)(tileM + wm * 64 + i * 16 + erow) * I_DIM + (tileN + wn * 64);
    *(uint4*)(gh + grow + echk * 8) = g0;
    *(uint4*)(gh + grow + (echk + 4) * 8) = g1;
    *(uint4*)(up + grow + echk * 8) = u0;
    *(uint4*)(up + grow + (echk + 4) * 8) = u1;
  }
  block_amax4(mxu, mxg, mxh, mxo, scal);
}

// GEMM2: oq[8192,3072] x wdq[1024,3072]^T -> out fp32 [8192,1024]
__global__ void __launch_bounds__(256) kgemm2(const u16* __restrict__ oq,
                                              const u16* __restrict__ wdq,
                                              float* __restrict__ out) {
  __shared__ __align__(16) u16 smem[16384];  // 32 KiB
  const int tileN = blockIdx.x * 128;
  const int tileM = blockIdx.y * 128;
  f32x4 acc[4][4];
#pragma unroll
  for (int i = 0; i < 4; ++i)
#pragma unroll
    for (int j = 0; j < 4; ++j) acc[i][j] = (f32x4){0.f, 0.f, 0.f, 0.f};
  gemm_core64<I_DIM>(oq + (size_t)tileM * I_DIM, wdq + (size_t)tileN * I_DIM, acc, smem);

  const int lane = threadIdx.x & 63, wave = threadIdx.x >> 6;
  const int wm = wave >> 1, wn = wave & 1;
  const int rb = (lane >> 4) * 4, cb = lane & 15;
#pragma unroll
  for (int i = 0; i < 4; ++i) {
#pragma unroll
    for (int j = 0; j < 4; ++j) {
      size_t base = (size_t)(tileM + wm * 64 + i * 16 + rb) * H_DIM +
                    (size_t)(tileN + wn * 64 + j * 16 + cb);
#pragma unroll
      for (int r = 0; r < 4; ++r) out[base + (size_t)r * H_DIM] = acc[i][j][r];
    }
  }
}

// ---------------- prep: absmax(x) (blocks 0..1023) + LPBQ dequant (rest) ----
__global__ void __launch_bounds__(256) kprep(const float* __restrict__ x,
                                             const float* __restrict__ wu,
                                             const float* __restrict__ wg,
                                             const float* __restrict__ wdn,
                                             u16* __restrict__ wcat, u16* __restrict__ wdq,
                                             u32* __restrict__ scal) {
  if (blockIdx.x < 1024) {
    const float4* x4 = (const float4*)x;
    const int n4 = (M_ROWS * H_DIM) / 4;
    float mx = 0.f;
    for (int i = blockIdx.x * 256 + threadIdx.x; i < n4; i += 1024 * 256) {
      float4 v = x4[i];
      mx = fmaxf(fmaxf(fabsf(v.x), fabsf(v.y)), fmaxf(fmaxf(fabsf(v.z), fabsf(v.w)), mx));
    }
    block_amax_atomic(mx, scal, 0);
    return;
  }
  const int gid = (blockIdx.x - 1024) * 256 + threadIdx.x;
  const int unit = gid >> 3, l8 = gid & 7;
  const float* src;
  u16* dst;
  int u;
  if (unit < 98304)       { src = wu;  dst = wcat;            u = unit; }
  else if (unit < 196608) { src = wg;  dst = wcat + 3145728;  u = unit - 98304; }
  else                    { src = wdn; dst = wdq;             u = unit - 196608; }
  const size_t off = (size_t)u * 32 + (size_t)l8 * 4;
  float4 v = *(const float4*)(src + off);
  float m = fmaxf(fmaxf(fabsf(v.x), fabsf(v.y)), fmaxf(fabsf(v.z), fabsf(v.w)));
  m = fmaxf(m, __shfl_xor(m, 1));
  m = fmaxf(m, __shfl_xor(m, 2));
  m = fmaxf(m, __shfl_xor(m, 4));
  const float s = fmaxf(m / 7.0f, 1e-12f);
  const float inv = 1.0f / s;
  float vv[4] = {v.x, v.y, v.z, v.w};
  u16 o[4];
#pragma unroll
  for (int e = 0; e < 4; ++e) {
    float q = rintf(vv[e] * inv);
    q = fminf(fmaxf(q, -8.f), 7.f);
    o[e] = f2bf(q * s);
  }
  *(ushort4*)(dst + off) = make_ushort4(o[0], o[1], o[2], o[3]);
}

__global__ void __launch_bounds__(256) kqdqx(const float4* __restrict__ x,
                                             ushort4* __restrict__ xq,
                                             const u32* __restrict__ scal) {
  const float s = scale_read(scal, 0);
  const float inv = 1.0f / s;
  const int i = blockIdx.x * 256 + threadIdx.x;
  float4 v = x[i];
  ushort4 o;
  o.x = f2bf(qdq16i(v.x, inv, s));
  o.y = f2bf(qdq16i(v.y, inv, s));
  o.z = f2bf(qdq16i(v.z, inv, s));
  o.w = f2bf(qdq16i(v.w, inv, s));
  xq[i] = o;
}

#define GH4 ((M_ROWS * I_DIM) / 8)
#define EW_BLOCKS 2048

// exact chain: g_q=qdq(g,sg); h=g_q*sigq(g_q); h_q=qdq(h,sh);
// o=h_q*qdq(u,su); oq=bf16(qdq(o,so)) -> gh (in place)
__global__ void __launch_bounds__(256) kmulo(uint4* __restrict__ gh, const uint4* __restrict__ up,
                                             u32* __restrict__ scal) {
  const float sg = scale_read(scal, 2), ig = 1.0f / sg;
  const float sh = scale_read(scal, 3), ih = 1.0f / sh;
  const float su = scale_read(scal, 1), iu = 1.0f / su;
  const float so = scale_read(scal, 4), io = 1.0f / so;
  for (int i = blockIdx.x * 256 + threadIdx.x; i < GH4; i += EW_BLOCKS * 256) {
    union { uint4 v; u16 us[8]; } a, b;
    a.v = gh[i];
    b.v = up[i];
#pragma unroll
    for (int e = 0; e < 8; ++e) {
      float g = qdq16i(bf2f(a.us[e]), ig, sg);
      float h = g * sigq(g);
      float o = qdq16i(h, ih, sh) * qdq16i(bf2f(b.us[e]), iu, su);
      a.us[e] = f2bf(qdq16i(o, io, so));
    }
    gh[i] = a.v;
  }
}

extern "C" void kernel_launch(void* const* d_in, const int* in_sizes, int n_in,
                              void* d_out, int out_size, void* d_ws, size_t ws_size,
                              hipStream_t stream) {
  (void)in_sizes; (void)n_in; (void)out_size; (void)ws_size;
  const float* x   = (const float*)d_in[0];
  const float* wg  = (const float*)d_in[1];
  const float* wu  = (const float*)d_in[2];
  const float* wdn = (const float*)d_in[3];
  float* out = (float*)d_out;
  char* ws = (char*)d_ws;

  u32* scal = (u32*)ws;
  u16* xq   = (u16*)(ws + 1024);                    // 8192*1024
  u16* wcat = xq + (size_t)M_ROWS * H_DIM;          // 6144*1024 (up rows, then gate rows)
  u16* wdq  = wcat + (size_t)2 * I_DIM * H_DIM;     // 1024*3072
  u16* up   = wdq + (size_t)H_DIM * I_DIM;          // 8192*3072
  u16* gh   = up + (size_t)M_ROWS * I_DIM;          // 8192*3072 (gate -> oq)

  hipMemsetAsync(scal, 0, 1024, stream);
  kprep<<<1024 + 9216, 256, 0, stream>>>(x, wu, wg, wdn, wcat, wdq, scal);
  kqdqx<<<(M_ROWS * H_DIM) / 4 / 256, 256, 0, stream>>>((const float4*)x, (ushort4*)xq, scal);
  kgemm1<<<dim3(24, 64), 256, 0, stream>>>(xq, wcat, up, gh, scal);
  kmulo<<<EW_BLOCKS, 256, 0, stream>>>((uint4*)gh, (const uint4*)up, scal);
  kgemm2<<<dim3(8, 64), 256, 0, stream>>>(gh, wdq, out);
}

// Round 3
// 322.633 us; speedup vs baseline: 1.2206x; 1.0019x over previous
//
#include <hip/hip_runtime.h>
#include <hip/hip_bf16.h>
#include <stdint.h>

// Qwen3 MLP with QDQ fake-quant, MI355X gfx950.
// M=8192 (B*S), H=1024, I=3072.
// R7: T3-minimum 2-phase pipeline on both GEMMs. Double-buffered LDS,
// stage(t+1) issued at top of iteration t, ONE __syncthreads per K-step
// (drain lands after ~64 MFMAs instead of serializing with the stage).
// kgemm1: BM=256 BN=128, 512 thr (8 waves), dual-B, LDS 128 KiB, 1 blk/CU.
// kgemm2: BM=256 BN=128, 512 thr, LDS 96 KiB, grid (8,32) = 1 blk/CU.
// launch_bounds(512,2) caps combined VGPR+AGPR at 256 (R6 lesson).

#define M_ROWS 8192
#define H_DIM 1024
#define I_DIM 3072

typedef unsigned short u16;
typedef unsigned int u32;
typedef __attribute__((ext_vector_type(8))) short bf16x8;
typedef __attribute__((ext_vector_type(4))) float f32x4;

__device__ __forceinline__ float bf2f(u16 v) { return __uint_as_float(((u32)v) << 16); }
__device__ __forceinline__ u16 f2bf(float f) {
  u32 u = __float_as_uint(f);
  u32 r = (u + 0x7fffu + ((u >> 16) & 1u)) >> 16;
  return (u16)r;
}
__device__ __forceinline__ float qdq16i(float x, float inv, float s) {
  float q = rintf(x * inv);
  q = fminf(fmaxf(q, -32768.f), 32767.f);
  return q * s;
}
// fixed u16 sigmoid grid
__device__ __forceinline__ float sigq(float g) {
  float sig = __builtin_amdgcn_rcpf(1.f + __expf(-g));
  return fminf(fmaxf(rintf(sig * 65536.f), 0.f), 65535.f) * (1.f / 65536.f);
}

// scal: u32[16][16]; sub-slot j of slot s at scal[j*16+s] (16 distinct 64B lines)
// slots: 0=x 1=up 2=gate 3=h 4=o
__device__ __forceinline__ float scale_read(const u32* __restrict__ scal, int s) {
  u32 m = 0;
#pragma unroll
  for (int j = 0; j < 16; ++j) m = max(m, scal[j * 16 + s]);
  return fmaxf(__uint_as_float(m) / 32767.f, 1e-12f);
}

__device__ __forceinline__ void load_lds16(const u16* g, u16* lds) {
  __builtin_amdgcn_global_load_lds(
      (const __attribute__((address_space(1))) u32*)g,
      (__attribute__((address_space(3))) u32*)lds, 16, 0, 0);
}

__device__ __forceinline__ void block_amax_atomic(float mx, u32* scal, int s) {
#pragma unroll
  for (int off = 32; off; off >>= 1) mx = fmaxf(mx, __shfl_xor(mx, off));
  __shared__ float red[4];
  const int lane = threadIdx.x & 63, wave = threadIdx.x >> 6;
  if (lane == 0) red[wave] = mx;
  __syncthreads();
  if (threadIdx.x == 0) {
    float m = fmaxf(fmaxf(red[0], red[1]), fmaxf(red[2], red[3]));
    atomicMax(scal + (blockIdx.x & 15) * 16 + s, __float_as_uint(m));
  }
}

// four amaxes, one barrier, 8-wave (512-thread) block; slots 1=up 2=gate 3=h 4=o
__device__ __forceinline__ void block_amax4_8w(float a, float b, float c, float d,
                                               u32* __restrict__ scal) {
#pragma unroll
  for (int off = 32; off; off >>= 1) {
    a = fmaxf(a, __shfl_xor(a, off));
    b = fmaxf(b, __shfl_xor(b, off));
    c = fmaxf(c, __shfl_xor(c, off));
    d = fmaxf(d, __shfl_xor(d, off));
  }
  __shared__ float red4[4][8];
  const int lane = threadIdx.x & 63, wave = threadIdx.x >> 6;
  if (lane == 0) {
    red4[0][wave] = a;
    red4[1][wave] = b;
    red4[2][wave] = c;
    red4[3][wave] = d;
  }
  __syncthreads();
  if (threadIdx.x == 0) {
    u32* base = scal + (blockIdx.x & 15) * 16;
#pragma unroll
    for (int s = 0; s < 4; ++s) {
      float m = 0.f;
#pragma unroll
      for (int w = 0; w < 8; ++w) m = fmaxf(m, red4[s][w]);
      atomicMax(base + 1 + s, __float_as_uint(m));
    }
  }
}

// GEMM1 fused 2-phase: BM=256 BN=128 BK=64, 512 threads (8 waves, 4Mx2N).
// Per wave: 64x64 of BOTH gate and up heads (acc 2x16 f32x4 = 128 AGPR).
// LDS: dbuf halves of [A 256x64 | Bu 128x64 | Bg 128x64] = 2 x 64 KiB.
// Swizzle: chunk q of row r at phys q^(r&7) (2-way = free); gload_lds dest
// linear, source pre-swizzled.
// Epilogue: 4 amaxes (h,o approximate: qdq-snap skipped, scale rel-err
// ~0.4% -> <1e-3 final absmax impact).
__global__ void __launch_bounds__(512, 2) kgemm1(const u16* __restrict__ xq,
                                                 const u16* __restrict__ wcat,
                                                 u16* __restrict__ up, u16* __restrict__ gh,
                                                 u32* __restrict__ scal) {
  __shared__ __align__(16) u16 smem[65536];  // 128 KiB: two 32768-u16 halves
  const int tileN = blockIdx.x * 128;
  const int tileM = blockIdx.y * 256;
  const int tid = threadIdx.x;
  const int lane = tid & 63, wave = tid >> 6;
  const int wm = wave >> 1, wn = wave & 1;  // 4 x 2 wave grid
  const int quad = lane >> 4, mrow = lane & 15;

  const u16* Ablk = xq + (size_t)tileM * H_DIM;
  const u16* Bublk = wcat + (size_t)tileN * H_DIM;
  const u16* Bgblk = wcat + (size_t)(I_DIM + tileN) * H_DIM;

  int goffA[4], loffA[4], goffB[2], loffB[2];
#pragma unroll
  for (int t = 0; t < 4; ++t) {
    const int c = tid + 512 * t;  // 2048 chunks of A (256x64)
    const int r = c >> 3, q = c & 7;
    goffA[t] = r * H_DIM + ((q ^ (r & 7)) << 3);
    loffA[t] = c << 3;
  }
#pragma unroll
  for (int t = 0; t < 2; ++t) {
    const int c = tid + 512 * t;  // 1024 chunks of B (128x64)
    const int r = c >> 3, q = c & 7;
    goffB[t] = r * H_DIM + ((q ^ (r & 7)) << 3);
    loffB[t] = c << 3;
  }
  const int pc0 = (quad ^ (mrow & 7)) << 3;
  const int pc1 = ((quad + 4) ^ (mrow & 7)) << 3;
  int arow[4], brow[4];
#pragma unroll
  for (int i = 0; i < 4; ++i) {
    arow[i] = (wm * 64 + i * 16 + mrow) << 6;
    brow[i] = (wn * 64 + i * 16 + mrow) << 6;
  }

  f32x4 accg[4][4], accu[4][4];
#pragma unroll
  for (int i = 0; i < 4; ++i)
#pragma unroll
    for (int j = 0; j < 4; ++j) {
      accg[i][j] = (f32x4){0.f, 0.f, 0.f, 0.f};
      accu[i][j] = (f32x4){0.f, 0.f, 0.f, 0.f};
    }

  // prologue: stage k0=0 into half 0
  {
    u16* d = smem;
#pragma unroll
    for (int t = 0; t < 4; ++t) load_lds16(Ablk + goffA[t], d + loffA[t]);
#pragma unroll
    for (int t = 0; t < 2; ++t) load_lds16(Bublk + goffB[t], d + 16384 + loffB[t]);
#pragma unroll
    for (int t = 0; t < 2; ++t) load_lds16(Bgblk + goffB[t], d + 24576 + loffB[t]);
  }
  __syncthreads();

  int cur = 0;
  for (int k0 = 0; k0 < H_DIM; k0 += 64) {
    // stage next tile into the other half (latency hidden under MFMAs below)
    if (k0 + 64 < H_DIM) {
      u16* d = smem + (cur ^ 1) * 32768;
      const int kn = k0 + 64;
#pragma unroll
      for (int t = 0; t < 4; ++t) load_lds16(Ablk + kn + goffA[t], d + loffA[t]);
#pragma unroll
      for (int t = 0; t < 2; ++t) load_lds16(Bublk + kn + goffB[t], d + 16384 + loffB[t]);
#pragma unroll
      for (int t = 0; t < 2; ++t) load_lds16(Bgblk + kn + goffB[t], d + 24576 + loffB[t]);
    }
    const u16* As = smem + cur * 32768;
    const u16* Bus = As + 16384;
    const u16* Bgs = As + 24576;
#pragma unroll
    for (int kk = 0; kk < 2; ++kk) {
      const int pc = kk ? pc1 : pc0;
      bf16x8 af[4];
#pragma unroll
      for (int t = 0; t < 4; ++t) af[t] = *(const bf16x8*)&As[arow[t] + pc];
      // one B fragment live at a time: keeps peak regs under the 256 cap
#pragma unroll
      for (int j = 0; j < 4; ++j) {
        bf16x8 b = *(const bf16x8*)&Bus[brow[j] + pc];
#pragma unroll
        for (int i = 0; i < 4; ++i)
          accu[i][j] = __builtin_amdgcn_mfma_f32_16x16x32_bf16(af[i], b, accu[i][j], 0, 0, 0);
      }
#pragma unroll
      for (int j = 0; j < 4; ++j) {
        bf16x8 b = *(const bf16x8*)&Bgs[brow[j] + pc];
#pragma unroll
        for (int i = 0; i < 4; ++i)
          accg[i][j] = __builtin_amdgcn_mfma_f32_16x16x32_bf16(af[i], b, accg[i][j], 0, 0, 0);
      }
    }
    __syncthreads();  // one drain per K-step, after compute
    cur ^= 1;
  }

  // ---------------- epilogue: both tiles + 4 amaxes ----------------
  const int rb = (lane >> 4) * 4, cb = lane & 15;  // C/D: row=(l>>4)*4+reg, col=l&15
  const int erow = lane >> 2, echk = lane & 3;
  u16* gstage = smem + wave * 1152;          // 8 waves * 16 rows * 72
  u16* ustage = smem + 16384 + wave * 1152;  // disjoint region
  const u16* grb = gstage + erow * 72;
  const u16* urb = ustage + erow * 72;
  float mxg = 0.f, mxu = 0.f, mxh = 0.f, mxo = 0.f;
#pragma unroll
  for (int i = 0; i < 4; ++i) {
    __syncthreads();
#pragma unroll
    for (int j = 0; j < 4; ++j)
#pragma unroll
      for (int r = 0; r < 4; ++r) {
        float g = accg[i][j][r];
        float u = accu[i][j][r];
        mxg = fmaxf(mxg, fabsf(g));
        mxu = fmaxf(mxu, fabsf(u));
        float ha = g * sigq(g);
        mxh = fmaxf(mxh, fabsf(ha));
        mxo = fmaxf(mxo, fabsf(ha * u));
        gstage[(rb + r) * 72 + j * 16 + cb] = f2bf(g);
        ustage[(rb + r) * 72 + j * 16 + cb] = f2bf(u);
      }
    __syncthreads();
    uint4 g0 = *(const uint4*)(grb + echk * 8);
    uint4 g1 = *(const uint4*)(grb + (echk + 4) * 8);
    uint4 u0 = *(const uint4*)(urb + echk * 8);
    uint4 u1 = *(const uint4*)(urb + (echk + 4) * 8);
    size_t grow = (size_t)(tileM + wm * 64 + i * 16 + erow) * I_DIM + (tileN + wn * 64);
    *(uint4*)(gh + grow + echk * 8) = g0;
    *(uint4*)(gh + grow + (echk + 4) * 8) = g1;
    *(uint4*)(up + grow + echk * 8) = u0;
    *(uint4*)(up + grow + (echk + 4) * 8) = u1;
  }
  block_amax4_8w(mxu, mxg, mxh, mxo, scal);
}

// GEMM2 2-phase: oq[8192,3072] x wdq[1024,3072]^T -> out fp32 [8192,1024].
// BM=256 BN=128 BK=64, 512 threads, dbuf LDS 96 KiB, grid (8,32)=1 blk/CU.
__global__ void __launch_bounds__(512, 2) kgemm2(const u16* __restrict__ oq,
                                                 const u16* __restrict__ wdq,
                                                 float* __restrict__ out) {
  __shared__ __align__(16) u16 smem[49152];  // 96 KiB: two 24576-u16 halves
  const int tileN = blockIdx.x * 128;
  const int tileM = blockIdx.y * 256;
  const int tid = threadIdx.x;
  const int lane = tid & 63, wave = tid >> 6;
  const int wm = wave >> 1, wn = wave & 1;
  const int quad = lane >> 4, mrow = lane & 15;

  const u16* Ablk = oq + (size_t)tileM * I_DIM;
  const u16* Bblk = wdq + (size_t)tileN * I_DIM;

  int goffA[4], loffA[4], goffB[2], loffB[2];
#pragma unroll
  for (int t = 0; t < 4; ++t) {
    const int c = tid + 512 * t;
    const int r = c >> 3, q = c & 7;
    goffA[t] = r * I_DIM + ((q ^ (r & 7)) << 3);
    loffA[t] = c << 3;
  }
#pragma unroll
  for (int t = 0; t < 2; ++t) {
    const int c = tid + 512 * t;
    const int r = c >> 3, q = c & 7;
    goffB[t] = r * I_DIM + ((q ^ (r & 7)) << 3);
    loffB[t] = c << 3;
  }
  const int pc0 = (quad ^ (mrow & 7)) << 3;
  const int pc1 = ((quad + 4) ^ (mrow & 7)) << 3;
  int arow[4], brow[4];
#pragma unroll
  for (int i = 0; i < 4; ++i) {
    arow[i] = (wm * 64 + i * 16 + mrow) << 6;
    brow[i] = (wn * 64 + i * 16 + mrow) << 6;
  }

  f32x4 acc[4][4];
#pragma unroll
  for (int i = 0; i < 4; ++i)
#pragma unroll
    for (int j = 0; j < 4; ++j) acc[i][j] = (f32x4){0.f, 0.f, 0.f, 0.f};

  {
    u16* d = smem;
#pragma unroll
    for (int t = 0; t < 4; ++t) load_lds16(Ablk + goffA[t], d + loffA[t]);
#pragma unroll
    for (int t = 0; t < 2; ++t) load_lds16(Bblk + goffB[t], d + 16384 + loffB[t]);
  }
  __syncthreads();

  int cur = 0;
  for (int k0 = 0; k0 < I_DIM; k0 += 64) {
    if (k0 + 64 < I_DIM) {
      u16* d = smem + (cur ^ 1) * 24576;
      const int kn = k0 + 64;
#pragma unroll
      for (int t = 0; t < 4; ++t) load_lds16(Ablk + kn + goffA[t], d + loffA[t]);
#pragma unroll
      for (int t = 0; t < 2; ++t) load_lds16(Bblk + kn + goffB[t], d + 16384 + loffB[t]);
    }
    const u16* As = smem + cur * 24576;
    const u16* Bs = As + 16384;
#pragma unroll
    for (int kk = 0; kk < 2; ++kk) {
      const int pc = kk ? pc1 : pc0;
      bf16x8 af[4];
#pragma unroll
      for (int t = 0; t < 4; ++t) af[t] = *(const bf16x8*)&As[arow[t] + pc];
#pragma unroll
      for (int j = 0; j < 4; ++j) {
        bf16x8 b = *(const bf16x8*)&Bs[brow[j] + pc];
#pragma unroll
        for (int i = 0; i < 4; ++i)
          acc[i][j] = __builtin_amdgcn_mfma_f32_16x16x32_bf16(af[i], b, acc[i][j], 0, 0, 0);
      }
    }
    __syncthreads();
    cur ^= 1;
  }

  const int rb = (lane >> 4) * 4, cb = lane & 15;
#pragma unroll
  for (int i = 0; i < 4; ++i) {
#pragma unroll
    for (int j = 0; j < 4; ++j) {
      size_t base = (size_t)(tileM + wm * 64 + i * 16 + rb) * H_DIM +
                    (size_t)(tileN + wn * 64 + j * 16 + cb);
#pragma unroll
      for (int r = 0; r < 4; ++r) out[base + (size_t)r * H_DIM] = acc[i][j][r];
    }
  }
}

// ---------------- prep: absmax(x) (blocks 0..1023) + LPBQ dequant (rest) ----
__global__ void __launch_bounds__(256) kprep(const float* __restrict__ x,
                                             const float* __restrict__ wu,
                                             const float* __restrict__ wg,
                                             const float* __restrict__ wdn,
                                             u16* __restrict__ wcat, u16* __restrict__ wdq,
                                             u32* __restrict__ scal) {
  if (blockIdx.x < 1024) {
    const float4* x4 = (const float4*)x;
    const int n4 = (M_ROWS * H_DIM) / 4;
    float mx = 0.f;
    for (int i = blockIdx.x * 256 + threadIdx.x; i < n4; i += 1024 * 256) {
      float4 v = x4[i];
      mx = fmaxf(fmaxf(fabsf(v.x), fabsf(v.y)), fmaxf(fmaxf(fabsf(v.z), fabsf(v.w)), mx));
    }
    block_amax_atomic(mx, scal, 0);
    return;
  }
  const int gid = (blockIdx.x - 1024) * 256 + threadIdx.x;
  const int unit = gid >> 3, l8 = gid & 7;
  const float* src;
  u16* dst;
  int u;
  if (unit < 98304)       { src = wu;  dst = wcat;            u = unit; }
  else if (unit < 196608) { src = wg;  dst = wcat + 3145728;  u = unit - 98304; }
  else                    { src = wdn; dst = wdq;             u = unit - 196608; }
  const size_t off = (size_t)u * 32 + (size_t)l8 * 4;
  float4 v = *(const float4*)(src + off);
  float m = fmaxf(fmaxf(fabsf(v.x), fabsf(v.y)), fmaxf(fabsf(v.z), fabsf(v.w)));
  m = fmaxf(m, __shfl_xor(m, 1));
  m = fmaxf(m, __shfl_xor(m, 2));
  m = fmaxf(m, __shfl_xor(m, 4));
  const float s = fmaxf(m / 7.0f, 1e-12f);
  const float inv = 1.0f / s;
  float vv[4] = {v.x, v.y, v.z, v.w};
  u16 o[4];
#pragma unroll
  for (int e = 0; e < 4; ++e) {
    float q = rintf(vv[e] * inv);
    q = fminf(fmaxf(q, -8.f), 7.f);
    o[e] = f2bf(q * s);
  }
  *(ushort4*)(dst + off) = make_ushort4(o[0], o[1], o[2], o[3]);
}

__global__ void __launch_bounds__(256) kqdqx(const float4* __restrict__ x,
                                             ushort4* __restrict__ xq,
                                             const u32* __restrict__ scal) {
  const float s = scale_read(scal, 0);
  const float inv = 1.0f / s;
  const int i = blockIdx.x * 256 + threadIdx.x;
  float4 v = x[i];
  ushort4 o;
  o.x = f2bf(qdq16i(v.x, inv, s));
  o.y = f2bf(qdq16i(v.y, inv, s));
  o.z = f2bf(qdq16i(v.z, inv, s));
  o.w = f2bf(qdq16i(v.w, inv, s));
  xq[i] = o;
}

#define GH4 ((M_ROWS * I_DIM) / 8)
#define EW_BLOCKS 2048

// exact chain: g_q=qdq(g,sg); h=g_q*sigq(g_q); h_q=qdq(h,sh);
// o=h_q*qdq(u,su); oq=bf16(qdq(o,so)) -> gh (in place)
__global__ void __launch_bounds__(256) kmulo(uint4* __restrict__ gh, const uint4* __restrict__ up,
                                             u32* __restrict__ scal) {
  const float sg = scale_read(scal, 2), ig = 1.0f / sg;
  const float sh = scale_read(scal, 3), ih = 1.0f / sh;
  const float su = scale_read(scal, 1), iu = 1.0f / su;
  const float so = scale_read(scal, 4), io = 1.0f / so;
  for (int i = blockIdx.x * 256 + threadIdx.x; i < GH4; i += EW_BLOCKS * 256) {
    union { uint4 v; u16 us[8]; } a, b;
    a.v = gh[i];
    b.v = up[i];
#pragma unroll
    for (int e = 0; e < 8; ++e) {
      float g = qdq16i(bf2f(a.us[e]), ig, sg);
      float h = g * sigq(g);
      float o = qdq16i(h, ih, sh) * qdq16i(bf2f(b.us[e]), iu, su);
      a.us[e] = f2bf(qdq16i(o, io, so));
    }
    gh[i] = a.v;
  }
}

extern "C" void kernel_launch(void* const* d_in, const int* in_sizes, int n_in,
                              void* d_out, int out_size, void* d_ws, size_t ws_size,
                              hipStream_t stream) {
  (void)in_sizes; (void)n_in; (void)out_size; (void)ws_size;
  const float* x   = (const float*)d_in[0];
  const float* wg  = (const float*)d_in[1];
  const float* wu  = (const float*)d_in[2];
  const float* wdn = (const float*)d_in[3];
  float* out = (float*)d_out;
  char* ws = (char*)d_ws;

  u32* scal = (u32*)ws;
  u16* xq   = (u16*)(ws + 1024);                    // 8192*1024
  u16* wcat = xq + (size_t)M_ROWS * H_DIM;          // 6144*1024 (up rows, then gate rows)
  u16* wdq  = wcat + (size_t)2 * I_DIM * H_DIM;     // 1024*3072
  u16* up   = wdq + (size_t)H_DIM * I_DIM;          // 8192*3072
  u16* gh   = up + (size_t)M_ROWS * I_DIM;          // 8192*3072 (gate -> oq)

  hipMemsetAsync(scal, 0, 1024, stream);
  kprep<<<1024 + 9216, 256, 0, stream>>>(x, wu, wg, wdn, wcat, wdq, scal);
  kqdqx<<<(M_ROWS * H_DIM) / 4 / 256, 256, 0, stream>>>((const float4*)x, (ushort4*)xq, scal);
  kgemm1<<<dim3(24, 32), 512, 0, stream>>>(xq, wcat, up, gh, scal);
  kmulo<<<EW_BLOCKS, 256, 0, stream>>>((uint4*)gh, (const uint4*)up, scal);
  kgemm2<<<dim3(8, 32), 512, 0, stream>>>(gh, wdq, out);
}